// Round 8
// baseline (489.729 us; speedup 1.0000x reference)
//
#include <hip/hip_runtime.h>
#include <hip/hip_bf16.h>
#include <cstdint>
#include <cstddef>

#define C_CLS   100000
#define D_FEAT  512
#define B_ROWS  512
#define NBN     391          /* ceil(100000/256) */
#define NBLK    (4 * NBN)    /* 1564 gemm blocks: 4 bm x 391 bn */

#define COSM 0.8775825618903728f
#define SINM 0.479425538604203f
#define TH_  (-0.8775825618903728f)
#define MM_  0.2397127693021015f   /* sin(0.5)*0.5 */

typedef __bf16 bf16x8 __attribute__((ext_vector_type(8)));
typedef float  f32x4  __attribute__((ext_vector_type(4)));

typedef __attribute__((address_space(3))) void lds_void;
typedef const __attribute__((address_space(1))) void g_void;

__device__ __forceinline__ void async_copy16(const void* g, void* l) {
    __builtin_amdgcn_global_load_lds((g_void*)g, (lds_void*)l, 16, 0, 0);
}

// ---------------- kernel 1: normalize ALL rows (w then x) -> bf16 ---------
// blocks 0..24999 handle w rows (4/block); blocks 25000..25127 handle x rows.
// Block 25000 additionally zeroes row_sum[512] and the ticket counter.
__global__ void k_norm(const float* __restrict__ x, const float* __restrict__ w,
                       __bf16* __restrict__ xn, __bf16* __restrict__ wn,
                       float* __restrict__ row_sum, int* __restrict__ counter) {
    const int r4   = blockIdx.x * 4 + (threadIdx.x >> 6);
    const int lane = threadIdx.x & 63;
    const float* src;
    __bf16*      dst;
    if (r4 < C_CLS) {
        src = w  + (size_t)r4 * D_FEAT;
        dst = wn + (size_t)r4 * D_FEAT;
    } else {
        src = x  + (size_t)(r4 - C_CLS) * D_FEAT;
        dst = xn + (size_t)(r4 - C_CLS) * D_FEAT;
    }
    const f32x4* p = (const f32x4*)src;
    f32x4 a = p[lane * 2];
    f32x4 b = p[lane * 2 + 1];
    float s = a[0]*a[0] + a[1]*a[1] + a[2]*a[2] + a[3]*a[3]
            + b[0]*b[0] + b[1]*b[1] + b[2]*b[2] + b[3]*b[3];
    #pragma unroll
    for (int m = 32; m >= 1; m >>= 1) s += __shfl_xor(s, m, 64);
    const float inv = 1.0f / fmaxf(sqrtf(s), 1e-12f);
    bf16x8 o;
    o[0] = (__bf16)(a[0]*inv); o[1] = (__bf16)(a[1]*inv);
    o[2] = (__bf16)(a[2]*inv); o[3] = (__bf16)(a[3]*inv);
    o[4] = (__bf16)(b[0]*inv); o[5] = (__bf16)(b[1]*inv);
    o[6] = (__bf16)(b[2]*inv); o[7] = (__bf16)(b[3]*inv);
    *(bf16x8*)(dst + lane * 8) = o;

    if (blockIdx.x == C_CLS / 4) {          // block 25000 (an x-block)
        row_sum[threadIdx.x]       = 0.0f;
        row_sum[threadIdx.x + 256] = 0.0f;
        if (threadIdx.x == 0) *counter = 0;
    }
}

// ---------------- kernel 2: 128x256 / BK=64 / 8-wave / triple-buffer ------
// One barrier + one counted vmcnt per 64-wide K-tile (8 total). The 3rd LDS
// buffer makes the prefetch target disjoint from the read buffer, removing
// the second barrier of the old 2-buffer loop. Prefetch distance = 2 K-tiles.
// Per-wave math (4x4 acc of 16x16x32, conflict-free 16-lane x 16B reads,
// ArcFace epilogue, ticket finalize) identical to the verified round-7 wave.
__global__ __launch_bounds__(512, 2) void k_gemm(
        const __bf16* __restrict__ xn, const __bf16* __restrict__ wn,
        const int* __restrict__ y,
        float* __restrict__ row_sum, float* __restrict__ tlogit,
        int* __restrict__ counter, float* __restrict__ out) {

    __shared__ __align__(16) __bf16 As[3][8192];    // [buf][(oct*128+row)*8] : 48 KB
    __shared__ __align__(16) __bf16 Bs[3][16384];   // [buf][(oct*256+row)*8] : 96 KB
    __shared__ int   ys[128];
    __shared__ float red[4][128];
    __shared__ int   lastflag;
    __shared__ float pr[8];

    const int tid = threadIdx.x;
    // bijective XCD swizzle: 1564 = 8*195 + 4 (m204 form)
    const int xcd = blockIdx.x & 7, o = blockIdx.x >> 3;
    const int wg  = (xcd < 4 ? xcd * 196 : 784 + (xcd - 4) * 195) + o;
    const int bm  = wg & 3;          // batch 128-row group
    const int bn  = wg >> 2;         // class 256-col group

    if (tid < 128) ys[tid] = y[bm * 128 + tid];

    const int wave = tid >> 6;       // 0..7
    const int lane = tid & 63;
    const int wm   = wave >> 2;      // 0..1 : 64-row half
    const int wn_  = wave & 3;       // 0..3 : 64-col quarter
    const int quad = lane >> 4;      // 0..3
    const int l15  = lane & 15;

    f32x4 acc[4][4];
    #pragma unroll
    for (int i = 0; i < 4; ++i)
        #pragma unroll
        for (int j = 0; j < 4; ++j) acc[i][j] = (f32x4){0.f, 0.f, 0.f, 0.f};

    // stage K-tile kt_ (64 cols) into buffer s: 6 global_load_lds / thread.
    // A: 1024 chunks, c -> oct=c>>7, row=c&127.  B: 2048 chunks, oct=c>>8, row=c&255.
    #define STAGE(s, kt_) do {                                                          \
        const int k0_ = (kt_) * 64;                                                     \
        _Pragma("unroll")                                                               \
        for (int i_ = 0; i_ < 2; ++i_) {                                                \
            const int c_ = tid + i_ * 512;                                              \
            async_copy16(xn + (size_t)(bm * 128 + (c_ & 127)) * D_FEAT + k0_ + (c_ >> 7) * 8, \
                         &As[s][c_ * 8]);                                               \
        }                                                                               \
        _Pragma("unroll")                                                               \
        for (int i_ = 0; i_ < 4; ++i_) {                                                \
            const int c_ = tid + i_ * 512;                                              \
            int grow_ = bn * 256 + (c_ & 255); if (grow_ > C_CLS - 1) grow_ = C_CLS - 1; \
            async_copy16(wn + (size_t)grow_ * D_FEAT + k0_ + (c_ >> 8) * 8,             \
                         &Bs[s][c_ * 8]);                                               \
        }                                                                               \
    } while (0)

    STAGE(0, 0);
    STAGE(1, 1);

    #pragma unroll
    for (int t = 0; t < 8; ++t) {               // 8 K-tiles of 64
        const int cur = t % 3;                  // compile-time under unroll

        // tile t's 6 loads done; tile t+1's 6 stay in flight
        if (t < 7) asm volatile("s_waitcnt vmcnt(6)" ::: "memory");
        else       asm volatile("s_waitcnt vmcnt(0)" ::: "memory");
        __builtin_amdgcn_s_barrier();
        // safe now: all waves finished reading buf[(t+2)%3] (= tile t-1's buf)
        if (t < 6) STAGE((t + 2) % 3, t + 2);

        #pragma unroll
        for (int ks = 0; ks < 2; ++ks) {        // two 32-wide slices
            bf16x8 af[4], bf[4];
            #pragma unroll
            for (int mi = 0; mi < 4; ++mi)
                af[mi] = *(const bf16x8*)&As[cur][((ks * 4 + quad) * 128 + wm * 64 + mi * 16 + l15) * 8];
            #pragma unroll
            for (int ni = 0; ni < 4; ++ni)
                bf[ni] = *(const bf16x8*)&Bs[cur][((ks * 4 + quad) * 256 + wn_ * 64 + ni * 16 + l15) * 8];
            __builtin_amdgcn_s_setprio(1);
            #pragma unroll
            for (int mi = 0; mi < 4; ++mi)
                #pragma unroll
                for (int ni = 0; ni < 4; ++ni)
                    acc[mi][ni] = __builtin_amdgcn_mfma_f32_16x16x32_bf16(af[mi], bf[ni], acc[mi][ni], 0, 0, 0);
            __builtin_amdgcn_s_setprio(0);
        }
    }
    #undef STAGE

    // ---- epilogue: cos -> margin -> exp(logit-64) -> per-row partials ----
    #pragma unroll
    for (int mi = 0; mi < 4; ++mi) {
        float rs[4] = {0.f, 0.f, 0.f, 0.f};
        #pragma unroll
        for (int ni = 0; ni < 4; ++ni) {
            const int gcol = bn * 256 + wn_ * 64 + ni * 16 + l15;
            const bool colv = (gcol < C_CLS);
            #pragma unroll
            for (int reg = 0; reg < 4; ++reg) {
                const int lrow = wm * 64 + mi * 16 + quad * 4 + reg;
                const float cosv = acc[mi][ni][reg];
                const float sinv = sqrtf(fmaxf(1.0f - cosv * cosv, 0.0f));
                const float phi  = (cosv > TH_) ? (cosv * COSM - sinv * SINM) : (cosv - MM_);
                const bool ist   = colv && (gcol == ys[lrow]);
                const float logit = 64.0f * (ist ? phi : cosv);
                if (ist) atomicExch(&tlogit[bm * 128 + lrow], logit);
                rs[reg] += colv ? __expf(logit - 64.0f) : 0.0f;
            }
        }
        #pragma unroll
        for (int reg = 0; reg < 4; ++reg) {
            float v = rs[reg];
            v += __shfl_xor(v, 8, 64);
            v += __shfl_xor(v, 4, 64);
            v += __shfl_xor(v, 2, 64);
            v += __shfl_xor(v, 1, 64);
            if (l15 == 0) red[wn_][wm * 64 + mi * 16 + quad * 4 + reg] = v;
        }
    }
    __syncthreads();
    if (tid < 128) {
        const float v = red[0][tid] + red[1][tid] + red[2][tid] + red[3][tid];
        atomicAdd(&row_sum[bm * 128 + tid], v);
    }

    // ---- ticket: last block finalizes the loss ---------------------------
    __syncthreads();
    if (tid == 0) {
        const int tkt = atomicAdd(counter, 1);
        lastflag = (tkt == NBLK - 1) ? 1 : 0;
    }
    __syncthreads();
    if (lastflag) {
        const float rsv = atomicAdd(&row_sum[tid], 0.0f);   // coherent read
        const float tlv = atomicAdd(&tlogit[tid], 0.0f);    // coherent read
        float part = logf(rsv) + 64.0f - tlv;
        #pragma unroll
        for (int m = 32; m >= 1; m >>= 1) part += __shfl_xor(part, m, 64);
        if ((tid & 63) == 0) pr[tid >> 6] = part;
        __syncthreads();
        if (tid == 0) {
            float s = 0.0f;
            #pragma unroll
            for (int i = 0; i < 8; ++i) s += pr[i];
            out[0] = s * (1.0f / 512.0f);
        }
    }
}

extern "C" void kernel_launch(void* const* d_in, const int* in_sizes, int n_in,
                              void* d_out, int out_size, void* d_ws, size_t ws_size,
                              hipStream_t stream) {
    const float* x = (const float*)d_in[0];
    const int*   y = (const int*)d_in[1];
    const float* w = (const float*)d_in[2];

    char* ws = (char*)d_ws;
    __bf16* xn      = (__bf16*)ws;                                // 524288 B
    __bf16* wn      = (__bf16*)(ws + 524288);                     // 102400000 B
    float*  row_sum = (float*)(ws + 524288 + 102400000);          // 2048 B
    float*  tlogit  = (float*)(ws + 524288 + 102400000 + 2048);   // 2048 B
    int*    counter = (int*)(ws + 524288 + 102400000 + 4096);     // 4 B
    float*  out     = (float*)d_out;

    hipLaunchKernelGGL(k_norm, dim3((C_CLS + B_ROWS) / 4), dim3(256), 0, stream,
                       x, w, xn, wn, row_sum, counter);
    hipLaunchKernelGGL(k_gemm, dim3(NBLK), dim3(512), 0, stream,
                       xn, wn, y, row_sum, tlogit, counter, out);
}